// Round 13
// baseline (246.873 us; speedup 1.0000x reference)
//
#include <hip/hip_runtime.h>
#include <hip/hip_bf16.h>

#define THREADS 256
#define BSHIFT 9              // 512 nodes per coarse bucket; NB = ceil(N/512) <= 256
#define BIN_CHUNK 4096        // edges per k_bin block (16/thread)
#define KP 136                // padded LDS row stride (shorts); KP*2=272 B, 16B-aligned

typedef __attribute__((ext_vector_type(8))) short bf16x8;
typedef __attribute__((ext_vector_type(8))) unsigned short u16x8;
typedef __attribute__((ext_vector_type(4))) float f32x4;

// ---------------- helpers ----------------

__device__ inline unsigned short f2bf(float f) {  // round-to-nearest-even
    unsigned int u = __float_as_uint(f);
    unsigned int r = (u + 0x7fffu + ((u >> 16) & 1u)) >> 16;
    return (unsigned short)r;
}

__device__ inline float2 bf2_to_f2(unsigned int u) {  // low bf16 -> x, high bf16 -> y
    float2 r;
    r.x = __uint_as_float(u << 16);
    r.y = __uint_as_float(u & 0xffff0000u);
    return r;
}

__device__ inline void accum_row_scaled(float* acc, uint4 v, float s) {
    float2 a = bf2_to_f2(v.x), b = bf2_to_f2(v.y), c = bf2_to_f2(v.z), d = bf2_to_f2(v.w);
    acc[0] = fmaf(s, a.x, acc[0]); acc[1] = fmaf(s, a.y, acc[1]);
    acc[2] = fmaf(s, b.x, acc[2]); acc[3] = fmaf(s, b.y, acc[3]);
    acc[4] = fmaf(s, c.x, acc[4]); acc[5] = fmaf(s, c.y, acc[5]);
    acc[6] = fmaf(s, d.x, acc[6]); acc[7] = fmaf(s, d.y, acc[7]);
}

__device__ inline void accum_row(float* acc, uint4 v) {
    float2 a = bf2_to_f2(v.x), b = bf2_to_f2(v.y), c = bf2_to_f2(v.z), d = bf2_to_f2(v.w);
    acc[0] += a.x; acc[1] += a.y; acc[2] += b.x; acc[3] += b.y;
    acc[4] += c.x; acc[5] += c.y; acc[6] += d.x; acc[7] += d.y;
}

// gather64 4-wide step: 4 rows (8 uint4 each) in flight, no register arrays
__device__ inline void g64_quad(const uint4* __restrict__ h4, int ep, int gbase, int k,
                                int l8, float* acc) {
    int i0 = __shfl(ep, gbase + k);
    int i1 = __shfl(ep, gbase + k + 1);
    int i2 = __shfl(ep, gbase + k + 2);
    int i3 = __shfl(ep, gbase + k + 3);
    uint4 v0 = h4[(size_t)i0 * 8 + l8];
    uint4 v1 = h4[(size_t)i1 * 8 + l8];
    uint4 v2 = h4[(size_t)i2 * 8 + l8];
    uint4 v3 = h4[(size_t)i3 * 8 + l8];
    accum_row(acc, v0);
    accum_row(acc, v1);
    accum_row(acc, v2);
    accum_row(acc, v3);
}

// build a B-fragment (bf16x8: 8 consecutive k) from row-major fp32 W[K x ldn]
__device__ inline bf16x8 load_bfrag(const float* __restrict__ W, int ldn, int k0, int col) {
    bf16x8 b;
#pragma unroll
    for (int i = 0; i < 8; ++i) b[i] = (short)f2bf(W[(size_t)(k0 + i) * ldn + col]);
    return b;
}

// ---------------- fused: edge binning (blocks [0,nbin)) + layer-1 GEMM (rest) ---------
// Bin role: block-local LDS bucket sort; per-record GLOBAL destination computed at
// scatter time (destg) so the copy phase is a flat fully-parallel loop with
// run-coalesced writes (R7 evidence: direct 4-B random scatter write-amplifies;
// R8's staged version failed on its 75%-idle per-bucket copy loop, fixed in R12).
// GEMM role: h[M x 128](bf16) = x[M x 128] @ W1 (unscaled; dinv folded into gather).

__global__ __launch_bounds__(256) void k_bin_gemm1(const int* __restrict__ src,
                                                   const int* __restrict__ dst,
                                                   int* __restrict__ bcur,
                                                   unsigned int* __restrict__ binned,
                                                   int E, int NB, int cap,
                                                   const float* __restrict__ x,
                                                   const float* __restrict__ W1,
                                                   unsigned short* __restrict__ h,
                                                   int M, int nbin) {
    __shared__ __align__(16) char smem[36864];  // bin: 4x256 int + staged[4096] + destg[4096]
    const int t = threadIdx.x;

    if ((int)blockIdx.x < nbin) {
        // ---------------- bin role ----------------
        int* bcnt = (int*)smem;            // [256] per-bucket counts
        int* bres = bcnt + 256;            // [256] global run base
        int* loc  = bres + 256;            // [256] inclusive scan of counts
        int* lcur = loc + 256;             // [256] staged scatter cursors
        unsigned int* staged = (unsigned int*)(lcur + 256);  // [4096]
        int* destg = (int*)(staged + 4096);                  // [4096]
        bcnt[t] = 0;
        __syncthreads();
        int base = blockIdx.x * BIN_CHUNK;
        int sv[16], dv[16];
#pragma unroll
        for (int i = 0; i < 4; ++i) {  // 4 x int4 = 16 edges/thread, vectorized
            int e0 = base + (i * 256 + t) * 4;
            if (e0 + 3 < E) {
                int4 s4 = *(const int4*)(src + e0);
                int4 d4 = *(const int4*)(dst + e0);
                sv[4 * i + 0] = s4.x; sv[4 * i + 1] = s4.y;
                sv[4 * i + 2] = s4.z; sv[4 * i + 3] = s4.w;
                dv[4 * i + 0] = d4.x; dv[4 * i + 1] = d4.y;
                dv[4 * i + 2] = d4.z; dv[4 * i + 3] = d4.w;
            } else {
                for (int k = 0; k < 4; ++k) {
                    int e = e0 + k;
                    if (e < E) { sv[4 * i + k] = src[e]; dv[4 * i + k] = dst[e]; }
                    else dv[4 * i + k] = -1;
                }
            }
        }
#pragma unroll
        for (int i = 0; i < 16; ++i)
            if (dv[i] >= 0) atomicAdd(&bcnt[dv[i] >> BSHIFT], 1);
        __syncthreads();
        if (t < NB) {
            int old = bcnt[t] ? atomicAdd(&bcur[t], bcnt[t]) : 0;
            bres[t] = t * cap + old;
        }
        loc[t] = bcnt[t];
        __syncthreads();
        for (int off = 1; off < 256; off <<= 1) {  // inclusive scan over buckets
            int add = (t >= off) ? loc[t - off] : 0;
            __syncthreads();
            loc[t] += add;
            __syncthreads();
        }
        lcur[t] = loc[t] - bcnt[t];  // exclusive start as scatter cursor
        __syncthreads();
#pragma unroll
        for (int i = 0; i < 16; ++i) {
            if (dv[i] >= 0) {
                int b = dv[i] >> BSHIFT;
                int p = atomicAdd(&lcur[b], 1);                 // local pos
                staged[p] = ((unsigned int)(dv[i] & 511) << 23) | (unsigned int)sv[i];
                int g = bres[b] + (p - (loc[b] - bcnt[b]));     // global dest
                destg[p] = (g < (b + 1) * cap) ? g : -1;        // overflow guard
            }
        }
        __syncthreads();
        int tot = loc[255];
        for (int k = t; k < tot; k += 256) {  // flat, run-coalesced copy
            int g = destg[k];
            if (g >= 0) binned[g] = staged[k];
        }
        return;
    }

    // ---------------- GEMM role: 64-row tile of h = x @ W1 ----------------
    short* As = (short*)smem;  // [64][KP] = 17,408 B
    const int m0 = ((int)blockIdx.x - nbin) * 64;
    {
        int ar = t >> 5;
        int ac = (t & 31) * 4;
#pragma unroll
        for (int rb = 0; rb < 64; rb += 8) {
            int lrow = rb + ar;
            int row = m0 + lrow;
            ushort4 sv = make_ushort4(0, 0, 0, 0);
            if (row < M) {
                float4 v = *(const float4*)(x + (size_t)row * 128 + ac);
                sv.x = f2bf(v.x); sv.y = f2bf(v.y); sv.z = f2bf(v.z); sv.w = f2bf(v.w);
            }
            *(ushort4*)&As[lrow * KP + ac] = sv;
        }
    }
    __syncthreads();

    const int w = t >> 6;
    const int lane = t & 63;
    const int lm = lane & 15;
    const int qd = lane >> 4;
    const int n0w = w * 32;

    f32x4 acc[4][2];
#pragma unroll
    for (int mi = 0; mi < 4; ++mi)
#pragma unroll
        for (int ni = 0; ni < 2; ++ni) acc[mi][ni] = (f32x4){0.f, 0.f, 0.f, 0.f};

#pragma unroll
    for (int ks = 0; ks < 4; ++ks) {
        bf16x8 b0 = load_bfrag(W1, 128, ks * 32 + qd * 8, n0w + lm);
        bf16x8 b1 = load_bfrag(W1, 128, ks * 32 + qd * 8, n0w + 16 + lm);
#pragma unroll
        for (int mi = 0; mi < 4; ++mi) {
            bf16x8 a = *(const bf16x8*)&As[(mi * 16 + lm) * KP + ks * 32 + qd * 8];
            acc[mi][0] = __builtin_amdgcn_mfma_f32_16x16x32_bf16(a, b0, acc[mi][0], 0, 0, 0);
            acc[mi][1] = __builtin_amdgcn_mfma_f32_16x16x32_bf16(a, b1, acc[mi][1], 0, 0, 0);
        }
    }

#pragma unroll
    for (int mi = 0; mi < 4; ++mi) {
#pragma unroll
        for (int ni = 0; ni < 2; ++ni) {
            int col = n0w + ni * 16 + lm;
#pragma unroll
            for (int r = 0; r < 4; ++r) {
                int lrow = mi * 16 + qd * 4 + r;
                int row = m0 + lrow;
                if (row < M) h[(size_t)row * 128 + col] = f2bf(acc[mi][ni][r]);
            }
        }
    }
}

// per-bucket, 512 threads (R11 win): histogram -> intra-bucket scan -> rp/deg/dinv,
// then place srcs into eperm via LDS cursors. Extra block (blockIdx == NB) converts
// W2 to transposed bf16 W2t[64][128] for the fused gather's GEMM tail.
__global__ __launch_bounds__(512) void k_node_place(const unsigned int* __restrict__ binned,
                                                    const int* __restrict__ bcur, int cap,
                                                    int* __restrict__ rp,
                                                    int* __restrict__ deg,
                                                    float* __restrict__ dinv,
                                                    int* __restrict__ eperm, int N,
                                                    const float* __restrict__ W2,
                                                    unsigned short* __restrict__ W2t, int NB) {
    int b = blockIdx.x;
    int t = threadIdx.x;
    if (b == NB) {  // W2[128 x 64] fp32 -> W2t[64 x 128] bf16
        for (int i = t; i < 64 * 128; i += 512) {
            int nn = i >> 7;
            int kk = i & 127;
            W2t[i] = f2bf(W2[(size_t)kk * 64 + nn]);
        }
        return;
    }
    __shared__ int lc[512];
    __shared__ int s[256];
    int beg = b * cap;
    int end = beg + min(bcur[b], cap);
    int d0 = b << BSHIFT;
    lc[t] = 0;
    __syncthreads();
    for (int j = beg + t; j < end; j += 512) atomicAdd(&lc[binned[j] >> 23], 1);
    __syncthreads();
    int a = 0, c = 0, pair = 0;
    if (t < 256) {
        a = lc[2 * t];
        c = lc[2 * t + 1];
        pair = a + c;
        s[t] = pair;
    }
    __syncthreads();
    for (int off = 1; off < 256; off <<= 1) {
        int add = (t >= off && t < 256) ? s[t - off] : 0;
        __syncthreads();
        if (t < 256) s[t] += add;
        __syncthreads();
    }
    int st0 = 0, st1 = 0;
    if (t < 256) {
        int excl = s[t] - pair;
        st0 = beg + excl;
        st1 = st0 + a;
        int node0 = d0 + 2 * t;
        if (node0 < N) {
            rp[node0] = st0;
            deg[node0] = a;
            dinv[node0] = rsqrtf((float)a + 1.0f);  // +1 = self-loop
        }
        if (node0 + 1 < N) {
            rp[node0 + 1] = st1;
            deg[node0 + 1] = c;
            dinv[node0 + 1] = rsqrtf((float)c + 1.0f);
        }
    }
    __syncthreads();
    if (t < 256) {
        lc[2 * t] = st0;           // repurpose lc as placement cursors
        lc[2 * t + 1] = st1;
    }
    __syncthreads();
    for (int j = beg + t; j < end; j += 512) {
        unsigned int p = binned[j];
        int pos = atomicAdd(&lc[p >> 23], 1);
        eperm[pos] = (int)(p & 0x7fffffu);
    }
}

// ---------------- fused: layer-1 gather + layer-2 GEMM (16-node blocks) ----------------
// R2's measured-best gather geometry + last-wave MFMA tail with LDS-bounced
// coalesced h2 row writes (R12).

__global__ __launch_bounds__(256) void k_gather_gemm2(const int* __restrict__ rp,
                                                      const int* __restrict__ deg,
                                                      const int* __restrict__ eperm,
                                                      const float* __restrict__ dinv,
                                                      const uint4* __restrict__ h4,  // bf16 rows: 16 uint4
                                                      const float* __restrict__ b1,
                                                      const unsigned short* __restrict__ W2t,  // bf16 [64][128]
                                                      unsigned short* __restrict__ h2,  // bf16 [n x 64]
                                                      int n) {
    __shared__ __align__(16) short As[16 * KP];   // 4,352 B
    __shared__ __align__(16) short outb[16 * 64]; // 2,048 B tail bounce
    __shared__ int done;

    const int t = threadIdx.x;
    const int lane = t & 63;
    const int l16 = lane & 15;
    const int gbase = lane & 48;
    const int m0 = blockIdx.x * 16;
    const int lrow = (t >> 6) * 4 + (lane >> 4);
    const int node = m0 + lrow;
    const bool valid = node < n;

    if (t == 0) done = 0;
    __syncthreads();  // cheap: all waves aligned at launch

    int beg = 0, end = 0;
    float dv_self = 0.f;
    if (valid) {
        beg = rp[node];
        end = beg + deg[node];
        dv_self = dinv[node];
    }

    float acc[8];
#pragma unroll
    for (int i = 0; i < 8; ++i) acc[i] = 0.f;
    if (valid) accum_row_scaled(acc, h4[(size_t)node * 16 + l16], dv_self);  // self-loop

    for (int j = beg; j < end; j += 16) {
        int cnt = end - j;
        if (cnt > 16) cnt = 16;
        int ep = eperm[j + (l16 < cnt ? l16 : cnt - 1)];
        float dvv = dinv[ep];
        int k = 0;
        for (; k + 4 <= cnt; k += 4) {
            int i0 = __shfl(ep, gbase + k);
            int i1 = __shfl(ep, gbase + k + 1);
            int i2 = __shfl(ep, gbase + k + 2);
            int i3 = __shfl(ep, gbase + k + 3);
            float d0 = __shfl(dvv, gbase + k);
            float d1 = __shfl(dvv, gbase + k + 1);
            float d2 = __shfl(dvv, gbase + k + 2);
            float d3 = __shfl(dvv, gbase + k + 3);
            uint4 v0 = h4[(size_t)i0 * 16 + l16];
            uint4 v1 = h4[(size_t)i1 * 16 + l16];
            uint4 v2 = h4[(size_t)i2 * 16 + l16];
            uint4 v3 = h4[(size_t)i3 * 16 + l16];
            accum_row_scaled(acc, v0, d0);
            accum_row_scaled(acc, v1, d1);
            accum_row_scaled(acc, v2, d2);
            accum_row_scaled(acc, v3, d3);
        }
        for (; k < cnt; ++k) {
            int i0 = __shfl(ep, gbase + k);
            float d0 = __shfl(dvv, gbase + k);
            uint4 v0 = h4[(size_t)i0 * 16 + l16];
            accum_row_scaled(acc, v0, d0);
        }
    }

    // layer-1 epilogue: relu(dinv*agg + b1) -> bf16 -> one 16-B LDS store
    {
        float4 bb0 = ((const float4*)b1)[l16 * 2];
        float4 bb1 = ((const float4*)b1)[l16 * 2 + 1];
        u16x8 s;
        s[0] = f2bf(fmaxf(fmaf(dv_self, acc[0], bb0.x), 0.f));
        s[1] = f2bf(fmaxf(fmaf(dv_self, acc[1], bb0.y), 0.f));
        s[2] = f2bf(fmaxf(fmaf(dv_self, acc[2], bb0.z), 0.f));
        s[3] = f2bf(fmaxf(fmaf(dv_self, acc[3], bb0.w), 0.f));
        s[4] = f2bf(fmaxf(fmaf(dv_self, acc[4], bb1.x), 0.f));
        s[5] = f2bf(fmaxf(fmaf(dv_self, acc[5], bb1.y), 0.f));
        s[6] = f2bf(fmaxf(fmaf(dv_self, acc[6], bb1.z), 0.f));
        s[7] = f2bf(fmaxf(fmaf(dv_self, acc[7], bb1.w), 0.f));
        *(u16x8*)&As[lrow * KP + l16 * 8] = s;  // 272-B row stride, 16-B aligned
    }

    // ---- last-wave tail: no block barrier ----
    __threadfence_block();  // drain this wave's LDS writes
    int lastv = 0;
    if (lane == 0) lastv = (atomicAdd(&done, 1) == 3) ? 1 : 0;
    lastv = __shfl(lastv, 0);
    if (!lastv) return;  // early waves free their SIMD slots

    const int lm = lane & 15;
    const int qd = lane >> 4;
#pragma unroll
    for (int wt = 0; wt < 4; ++wt) {  // all 4 column tiles -> LDS bounce
        const int col = wt * 16 + lm;
        f32x4 c4 = (f32x4){0.f, 0.f, 0.f, 0.f};
#pragma unroll
        for (int ks = 0; ks < 4; ++ks) {
            bf16x8 b = *(const bf16x8*)&W2t[(size_t)col * 128 + ks * 32 + qd * 8];
            bf16x8 a = *(const bf16x8*)&As[lm * KP + ks * 32 + qd * 8];
            c4 = __builtin_amdgcn_mfma_f32_16x16x32_bf16(a, b, c4, 0, 0, 0);
        }
#pragma unroll
        for (int r = 0; r < 4; ++r) {
            int r16 = qd * 4 + r;
            int row = m0 + r16;
            float dvr = (row < n) ? dinv[row] : 0.f;
            outb[r16 * 64 + col] = (short)f2bf(dvr * c4[r]);
        }
    }
    // coalesced full-row writes: 16 rows x 128 B = 2 iterations of 64 x uint4
#pragma unroll
    for (int it = 0; it < 2; ++it) {
        int idx = it * 64 + lane;
        int r16 = idx >> 3;
        int q = idx & 7;
        int row = m0 + r16;
        if (row < n)
            ((uint4*)(h2 + (size_t)row * 64))[q] = ((const uint4*)outb)[r16 * 8 + q];
    }
}

// 64-feature layer: 8 nodes/wave, 8 lanes/node (rows are 128 B). fp32 output.
// h2 (12.8 MB) is L2/L3-resident -> latency-bound regime: use the R2-proven
// 4-wide no-array ladder (~40 VGPR) instead of R3's v[16] batches (~100 VGPR)
// to restore full 8 blocks/CU occupancy (rule #23: R3's concurrency-null was
// measured in the throughput-pinned L2-miss regime; it does not transfer here).
__global__ __launch_bounds__(256) void k_gather64(const int* __restrict__ rp,
                                                  const int* __restrict__ deg,
                                                  const int* __restrict__ eperm,
                                                  const float* __restrict__ dinv,
                                                  const uint4* __restrict__ h4,  // bf16 rows: 8 uint4/row
                                                  const float* __restrict__ bias,
                                                  float* __restrict__ out, int n) {
    const int t = threadIdx.x;
    const int lane = t & 63;
    const int l8 = lane & 7;
    const int gbase = lane & 56;
    const int node = blockIdx.x * 32 + (t >> 6) * 8 + (lane >> 3);
    const bool valid = node < n;

    int beg = 0, end = 0;
    if (valid) {
        beg = rp[node];
        end = beg + deg[node];
    }

    float acc[8];
#pragma unroll
    for (int i = 0; i < 8; ++i) acc[i] = 0.f;
    if (valid) accum_row(acc, h4[(size_t)node * 8 + l8]);  // self

    int j = beg;
    // ---- full 16-edge batches: 2 index loads, 4x 4-wide steps ----
    for (; j + 16 <= end; j += 16) {
        int ep0 = eperm[j + l8];
        int ep1 = eperm[j + 8 + l8];
        g64_quad(h4, ep0, gbase, 0, l8, acc);
        g64_quad(h4, ep0, gbase, 4, l8, acc);
        g64_quad(h4, ep1, gbase, 0, l8, acc);
        g64_quad(h4, ep1, gbase, 4, l8, acc);
    }
    int cnt = end - j;
    // ---- one 8-edge batch if present ----
    if (cnt >= 8) {
        int ep = eperm[j + l8];
        g64_quad(h4, ep, gbase, 0, l8, acc);
        g64_quad(h4, ep, gbase, 4, l8, acc);
        j += 8;
        cnt -= 8;
    }
    // ---- remainder (< 8 edges) ----
    if (cnt > 0) {
        int ep = eperm[j + (l8 < cnt ? l8 : cnt - 1)];
        int k = 0;
        for (; k + 4 <= cnt; k += 4) g64_quad(h4, ep, gbase, k, l8, acc);
        for (; k < cnt; ++k) {
            int i0 = __shfl(ep, gbase + k);
            uint4 v0 = h4[(size_t)i0 * 8 + l8];
            accum_row(acc, v0);
        }
    }

    if (valid) {
        float dv = dinv[node];
        float4 b0 = ((const float4*)bias)[l8 * 2];
        float4 b1 = ((const float4*)bias)[l8 * 2 + 1];
        float4 o0, o1;
        o0.x = dv * acc[0] + b0.x; o0.y = dv * acc[1] + b0.y;
        o0.z = dv * acc[2] + b0.z; o0.w = dv * acc[3] + b0.w;
        o1.x = dv * acc[4] + b1.x; o1.y = dv * acc[5] + b1.y;
        o1.z = dv * acc[6] + b1.z; o1.w = dv * acc[7] + b1.w;
        float4* orow = (float4*)(out + (size_t)node * 64);
        orow[l8 * 2] = o0;
        orow[l8 * 2 + 1] = o1;
    }
}

// ---------------- launch ----------------

extern "C" void kernel_launch(void* const* d_in, const int* in_sizes, int n_in,
                              void* d_out, int out_size, void* d_ws, size_t ws_size,
                              hipStream_t stream) {
    const float* x  = (const float*)d_in[0];
    const int*   ei = (const int*)d_in[1];
    const float* W1 = (const float*)d_in[2];
    const float* b1 = (const float*)d_in[3];
    const float* W2 = (const float*)d_in[4];
    const float* b2 = (const float*)d_in[5];
    float* out = (float*)d_out;

    const int N = in_sizes[0] / 128;
    const int E = in_sizes[1] / 2;
    const int* src = ei;
    const int* dst = ei + E;
    const int NB = (N + 511) >> BSHIFT;                          // coarse buckets (<= 256)
    const int cap = (E + NB - 1) / NB + ((E / NB) >> 2) + 1024;  // padded window (mean+25%+1024)

    char* ws = (char*)d_ws;
    size_t off = 0;
    auto carve = [&](size_t bytes) -> void* {
        void* p = ws + off;
        off = (off + bytes + 255) & ~(size_t)255;
        return p;
    };
    float* dinv = (float*)carve((size_t)N * 4);
    int*   rp   = (int*)carve((size_t)N * 4);
    int*   deg  = (int*)carve((size_t)N * 4);
    int*   bcur = (int*)carve(256 * 4);
    unsigned int* binned = (unsigned int*)carve((size_t)NB * cap * 4);  // packed (dlocal,src)
    int*   eperm = (int*)carve((size_t)NB * cap * 4);                   // src, bucket-windowed
    unsigned short* h   = (unsigned short*)carve((size_t)N * 128 * 2);  // bf16 h = x@W1 (unscaled)
    unsigned short* h2  = (unsigned short*)carve((size_t)N * 64 * 2);   // bf16 layer-2 GEMM out
    unsigned short* W2t = (unsigned short*)carve(64 * 128 * 2);         // bf16 W2 transposed

    const int gMm = (N + 63) / 64;
    const int nbin = (E + BIN_CHUNK - 1) / BIN_CHUNK;

    // ---- CSR build overlapped with layer-1 GEMM ----
    hipMemsetAsync(bcur, 0, 256 * sizeof(int), stream);
    k_bin_gemm1<<<nbin + gMm, THREADS, 0, stream>>>(src, dst, bcur, binned, E, NB, cap,
                                                    x, W1, h, N, nbin);
    k_node_place<<<NB + 1, 512, 0, stream>>>(binned, bcur, cap, rp, deg, dinv, eperm, N,
                                             W2, W2t, NB);

    // ---- layer-1 gather fused with layer-2 GEMM (16-node blocks) ----
    k_gather_gemm2<<<(N + 15) / 16, THREADS, 0, stream>>>(rp, deg, eperm, dinv, (const uint4*)h,
                                                          b1, W2t, h2, N);

    // ---- layer-2 gather ----
    k_gather64<<<(N + 31) / 32, THREADS, 0, stream>>>(rp, deg, eperm, dinv, (const uint4*)h2, b2, out, N);
}

// Round 14
// 241.849 us; speedup vs baseline: 1.0208x; 1.0208x over previous
//
#include <hip/hip_runtime.h>
#include <hip/hip_bf16.h>

#define THREADS 256
#define BSHIFT 9              // 512 nodes per coarse bucket; NB = ceil(N/512) <= 256
#define BIN_CHUNK 4096        // edges per k_bin block (16/thread)
#define KP 136                // padded LDS row stride (shorts); KP*2=272 B, 16B-aligned

typedef __attribute__((ext_vector_type(8))) short bf16x8;
typedef __attribute__((ext_vector_type(8))) unsigned short u16x8;
typedef __attribute__((ext_vector_type(4))) float f32x4;

// ---------------- helpers ----------------

__device__ inline unsigned short f2bf(float f) {  // round-to-nearest-even
    unsigned int u = __float_as_uint(f);
    unsigned int r = (u + 0x7fffu + ((u >> 16) & 1u)) >> 16;
    return (unsigned short)r;
}

__device__ inline float2 bf2_to_f2(unsigned int u) {  // low bf16 -> x, high bf16 -> y
    float2 r;
    r.x = __uint_as_float(u << 16);
    r.y = __uint_as_float(u & 0xffff0000u);
    return r;
}

__device__ inline void accum_row_scaled(float* acc, uint4 v, float s) {
    float2 a = bf2_to_f2(v.x), b = bf2_to_f2(v.y), c = bf2_to_f2(v.z), d = bf2_to_f2(v.w);
    acc[0] = fmaf(s, a.x, acc[0]); acc[1] = fmaf(s, a.y, acc[1]);
    acc[2] = fmaf(s, b.x, acc[2]); acc[3] = fmaf(s, b.y, acc[3]);
    acc[4] = fmaf(s, c.x, acc[4]); acc[5] = fmaf(s, c.y, acc[5]);
    acc[6] = fmaf(s, d.x, acc[6]); acc[7] = fmaf(s, d.y, acc[7]);
}

__device__ inline void accum_row(float* acc, uint4 v) {
    float2 a = bf2_to_f2(v.x), b = bf2_to_f2(v.y), c = bf2_to_f2(v.z), d = bf2_to_f2(v.w);
    acc[0] += a.x; acc[1] += a.y; acc[2] += b.x; acc[3] += b.y;
    acc[4] += c.x; acc[5] += c.y; acc[6] += d.x; acc[7] += d.y;
}

// build a B-fragment (bf16x8: 8 consecutive k) from row-major fp32 W[K x ldn]
__device__ inline bf16x8 load_bfrag(const float* __restrict__ W, int ldn, int k0, int col) {
    bf16x8 b;
#pragma unroll
    for (int i = 0; i < 8; ++i) b[i] = (short)f2bf(W[(size_t)(k0 + i) * ldn + col]);
    return b;
}

// ---------------- fused: edge binning (blocks [0,nbin)) + layer-1 GEMM (rest) ---------
// Bin role: block-local LDS bucket sort; per-record GLOBAL destination computed at
// scatter time (destg) so the copy phase is a flat fully-parallel loop with
// run-coalesced writes (R7 evidence: direct 4-B random scatter write-amplifies;
// R8's staged version failed on its 75%-idle per-bucket copy loop, fixed in R12).
// GEMM role: h[M x 128](bf16) = x[M x 128] @ W1 (unscaled; dinv folded into gather).

__global__ __launch_bounds__(256) void k_bin_gemm1(const int* __restrict__ src,
                                                   const int* __restrict__ dst,
                                                   int* __restrict__ bcur,
                                                   unsigned int* __restrict__ binned,
                                                   int E, int NB, int cap,
                                                   const float* __restrict__ x,
                                                   const float* __restrict__ W1,
                                                   unsigned short* __restrict__ h,
                                                   int M, int nbin) {
    __shared__ __align__(16) char smem[36864];  // bin: 4x256 int + staged[4096] + destg[4096]
    const int t = threadIdx.x;

    if ((int)blockIdx.x < nbin) {
        // ---------------- bin role ----------------
        int* bcnt = (int*)smem;            // [256] per-bucket counts
        int* bres = bcnt + 256;            // [256] global run base
        int* loc  = bres + 256;            // [256] inclusive scan of counts
        int* lcur = loc + 256;             // [256] staged scatter cursors
        unsigned int* staged = (unsigned int*)(lcur + 256);  // [4096]
        int* destg = (int*)(staged + 4096);                  // [4096]
        bcnt[t] = 0;
        __syncthreads();
        int base = blockIdx.x * BIN_CHUNK;
        int sv[16], dv[16];
#pragma unroll
        for (int i = 0; i < 4; ++i) {  // 4 x int4 = 16 edges/thread, vectorized
            int e0 = base + (i * 256 + t) * 4;
            if (e0 + 3 < E) {
                int4 s4 = *(const int4*)(src + e0);
                int4 d4 = *(const int4*)(dst + e0);
                sv[4 * i + 0] = s4.x; sv[4 * i + 1] = s4.y;
                sv[4 * i + 2] = s4.z; sv[4 * i + 3] = s4.w;
                dv[4 * i + 0] = d4.x; dv[4 * i + 1] = d4.y;
                dv[4 * i + 2] = d4.z; dv[4 * i + 3] = d4.w;
            } else {
                for (int k = 0; k < 4; ++k) {
                    int e = e0 + k;
                    if (e < E) { sv[4 * i + k] = src[e]; dv[4 * i + k] = dst[e]; }
                    else dv[4 * i + k] = -1;
                }
            }
        }
#pragma unroll
        for (int i = 0; i < 16; ++i)
            if (dv[i] >= 0) atomicAdd(&bcnt[dv[i] >> BSHIFT], 1);
        __syncthreads();
        if (t < NB) {
            int old = bcnt[t] ? atomicAdd(&bcur[t], bcnt[t]) : 0;
            bres[t] = t * cap + old;
        }
        loc[t] = bcnt[t];
        __syncthreads();
        for (int off = 1; off < 256; off <<= 1) {  // inclusive scan over buckets
            int add = (t >= off) ? loc[t - off] : 0;
            __syncthreads();
            loc[t] += add;
            __syncthreads();
        }
        lcur[t] = loc[t] - bcnt[t];  // exclusive start as scatter cursor
        __syncthreads();
#pragma unroll
        for (int i = 0; i < 16; ++i) {
            if (dv[i] >= 0) {
                int b = dv[i] >> BSHIFT;
                int p = atomicAdd(&lcur[b], 1);                 // local pos
                staged[p] = ((unsigned int)(dv[i] & 511) << 23) | (unsigned int)sv[i];
                int g = bres[b] + (p - (loc[b] - bcnt[b]));     // global dest
                destg[p] = (g < (b + 1) * cap) ? g : -1;        // overflow guard
            }
        }
        __syncthreads();
        int tot = loc[255];
        for (int k = t; k < tot; k += 256) {  // flat, run-coalesced copy
            int g = destg[k];
            if (g >= 0) binned[g] = staged[k];
        }
        return;
    }

    // ---------------- GEMM role: 64-row tile of h = x @ W1 ----------------
    short* As = (short*)smem;  // [64][KP] = 17,408 B
    const int m0 = ((int)blockIdx.x - nbin) * 64;
    {
        int ar = t >> 5;
        int ac = (t & 31) * 4;
#pragma unroll
        for (int rb = 0; rb < 64; rb += 8) {
            int lrow = rb + ar;
            int row = m0 + lrow;
            ushort4 sv = make_ushort4(0, 0, 0, 0);
            if (row < M) {
                float4 v = *(const float4*)(x + (size_t)row * 128 + ac);
                sv.x = f2bf(v.x); sv.y = f2bf(v.y); sv.z = f2bf(v.z); sv.w = f2bf(v.w);
            }
            *(ushort4*)&As[lrow * KP + ac] = sv;
        }
    }
    __syncthreads();

    const int w = t >> 6;
    const int lane = t & 63;
    const int lm = lane & 15;
    const int qd = lane >> 4;
    const int n0w = w * 32;

    f32x4 acc[4][2];
#pragma unroll
    for (int mi = 0; mi < 4; ++mi)
#pragma unroll
        for (int ni = 0; ni < 2; ++ni) acc[mi][ni] = (f32x4){0.f, 0.f, 0.f, 0.f};

#pragma unroll
    for (int ks = 0; ks < 4; ++ks) {
        bf16x8 b0 = load_bfrag(W1, 128, ks * 32 + qd * 8, n0w + lm);
        bf16x8 b1 = load_bfrag(W1, 128, ks * 32 + qd * 8, n0w + 16 + lm);
#pragma unroll
        for (int mi = 0; mi < 4; ++mi) {
            bf16x8 a = *(const bf16x8*)&As[(mi * 16 + lm) * KP + ks * 32 + qd * 8];
            acc[mi][0] = __builtin_amdgcn_mfma_f32_16x16x32_bf16(a, b0, acc[mi][0], 0, 0, 0);
            acc[mi][1] = __builtin_amdgcn_mfma_f32_16x16x32_bf16(a, b1, acc[mi][1], 0, 0, 0);
        }
    }

#pragma unroll
    for (int mi = 0; mi < 4; ++mi) {
#pragma unroll
        for (int ni = 0; ni < 2; ++ni) {
            int col = n0w + ni * 16 + lm;
#pragma unroll
            for (int r = 0; r < 4; ++r) {
                int lrow = mi * 16 + qd * 4 + r;
                int row = m0 + lrow;
                if (row < M) h[(size_t)row * 128 + col] = f2bf(acc[mi][ni][r]);
            }
        }
    }
}

// per-bucket, 512 threads (R11 win): histogram -> intra-bucket scan -> rp/deg/dinv,
// then place srcs into eperm via LDS cursors. Extra block (blockIdx == NB) converts
// W2 to transposed bf16 W2t[64][128] for the fused gather's GEMM tail.
__global__ __launch_bounds__(512) void k_node_place(const unsigned int* __restrict__ binned,
                                                    const int* __restrict__ bcur, int cap,
                                                    int* __restrict__ rp,
                                                    int* __restrict__ deg,
                                                    float* __restrict__ dinv,
                                                    int* __restrict__ eperm, int N,
                                                    const float* __restrict__ W2,
                                                    unsigned short* __restrict__ W2t, int NB) {
    int b = blockIdx.x;
    int t = threadIdx.x;
    if (b == NB) {  // W2[128 x 64] fp32 -> W2t[64 x 128] bf16
        for (int i = t; i < 64 * 128; i += 512) {
            int nn = i >> 7;
            int kk = i & 127;
            W2t[i] = f2bf(W2[(size_t)kk * 64 + nn]);
        }
        return;
    }
    __shared__ int lc[512];
    __shared__ int s[256];
    int beg = b * cap;
    int end = beg + min(bcur[b], cap);
    int d0 = b << BSHIFT;
    lc[t] = 0;
    __syncthreads();
    for (int j = beg + t; j < end; j += 512) atomicAdd(&lc[binned[j] >> 23], 1);
    __syncthreads();
    int a = 0, c = 0, pair = 0;
    if (t < 256) {
        a = lc[2 * t];
        c = lc[2 * t + 1];
        pair = a + c;
        s[t] = pair;
    }
    __syncthreads();
    for (int off = 1; off < 256; off <<= 1) {
        int add = (t >= off && t < 256) ? s[t - off] : 0;
        __syncthreads();
        if (t < 256) s[t] += add;
        __syncthreads();
    }
    int st0 = 0, st1 = 0;
    if (t < 256) {
        int excl = s[t] - pair;
        st0 = beg + excl;
        st1 = st0 + a;
        int node0 = d0 + 2 * t;
        if (node0 < N) {
            rp[node0] = st0;
            deg[node0] = a;
            dinv[node0] = rsqrtf((float)a + 1.0f);  // +1 = self-loop
        }
        if (node0 + 1 < N) {
            rp[node0 + 1] = st1;
            deg[node0 + 1] = c;
            dinv[node0 + 1] = rsqrtf((float)c + 1.0f);
        }
    }
    __syncthreads();
    if (t < 256) {
        lc[2 * t] = st0;           // repurpose lc as placement cursors
        lc[2 * t + 1] = st1;
    }
    __syncthreads();
    for (int j = beg + t; j < end; j += 512) {
        unsigned int p = binned[j];
        int pos = atomicAdd(&lc[p >> 23], 1);
        eperm[pos] = (int)(p & 0x7fffffu);
    }
}

// ---------------- fused: layer-1 gather + layer-2 GEMM (16-node blocks) ----------------
// R2's measured-best gather geometry + last-wave MFMA tail with LDS-bounced
// coalesced h2 row writes (R12).

__global__ __launch_bounds__(256) void k_gather_gemm2(const int* __restrict__ rp,
                                                      const int* __restrict__ deg,
                                                      const int* __restrict__ eperm,
                                                      const float* __restrict__ dinv,
                                                      const uint4* __restrict__ h4,  // bf16 rows: 16 uint4
                                                      const float* __restrict__ b1,
                                                      const unsigned short* __restrict__ W2t,  // bf16 [64][128]
                                                      unsigned short* __restrict__ h2,  // bf16 [n x 64]
                                                      int n) {
    __shared__ __align__(16) short As[16 * KP];   // 4,352 B
    __shared__ __align__(16) short outb[16 * 64]; // 2,048 B tail bounce
    __shared__ int done;

    const int t = threadIdx.x;
    const int lane = t & 63;
    const int l16 = lane & 15;
    const int gbase = lane & 48;
    const int m0 = blockIdx.x * 16;
    const int lrow = (t >> 6) * 4 + (lane >> 4);
    const int node = m0 + lrow;
    const bool valid = node < n;

    if (t == 0) done = 0;
    __syncthreads();  // cheap: all waves aligned at launch

    int beg = 0, end = 0;
    float dv_self = 0.f;
    if (valid) {
        beg = rp[node];
        end = beg + deg[node];
        dv_self = dinv[node];
    }

    float acc[8];
#pragma unroll
    for (int i = 0; i < 8; ++i) acc[i] = 0.f;
    if (valid) accum_row_scaled(acc, h4[(size_t)node * 16 + l16], dv_self);  // self-loop

    for (int j = beg; j < end; j += 16) {
        int cnt = end - j;
        if (cnt > 16) cnt = 16;
        int ep = eperm[j + (l16 < cnt ? l16 : cnt - 1)];
        float dvv = dinv[ep];
        int k = 0;
        for (; k + 4 <= cnt; k += 4) {
            int i0 = __shfl(ep, gbase + k);
            int i1 = __shfl(ep, gbase + k + 1);
            int i2 = __shfl(ep, gbase + k + 2);
            int i3 = __shfl(ep, gbase + k + 3);
            float d0 = __shfl(dvv, gbase + k);
            float d1 = __shfl(dvv, gbase + k + 1);
            float d2 = __shfl(dvv, gbase + k + 2);
            float d3 = __shfl(dvv, gbase + k + 3);
            uint4 v0 = h4[(size_t)i0 * 16 + l16];
            uint4 v1 = h4[(size_t)i1 * 16 + l16];
            uint4 v2 = h4[(size_t)i2 * 16 + l16];
            uint4 v3 = h4[(size_t)i3 * 16 + l16];
            accum_row_scaled(acc, v0, d0);
            accum_row_scaled(acc, v1, d1);
            accum_row_scaled(acc, v2, d2);
            accum_row_scaled(acc, v3, d3);
        }
        for (; k < cnt; ++k) {
            int i0 = __shfl(ep, gbase + k);
            float d0 = __shfl(dvv, gbase + k);
            uint4 v0 = h4[(size_t)i0 * 16 + l16];
            accum_row_scaled(acc, v0, d0);
        }
    }

    // layer-1 epilogue: relu(dinv*agg + b1) -> bf16 -> one 16-B LDS store
    {
        float4 bb0 = ((const float4*)b1)[l16 * 2];
        float4 bb1 = ((const float4*)b1)[l16 * 2 + 1];
        u16x8 s;
        s[0] = f2bf(fmaxf(fmaf(dv_self, acc[0], bb0.x), 0.f));
        s[1] = f2bf(fmaxf(fmaf(dv_self, acc[1], bb0.y), 0.f));
        s[2] = f2bf(fmaxf(fmaf(dv_self, acc[2], bb0.z), 0.f));
        s[3] = f2bf(fmaxf(fmaf(dv_self, acc[3], bb0.w), 0.f));
        s[4] = f2bf(fmaxf(fmaf(dv_self, acc[4], bb1.x), 0.f));
        s[5] = f2bf(fmaxf(fmaf(dv_self, acc[5], bb1.y), 0.f));
        s[6] = f2bf(fmaxf(fmaf(dv_self, acc[6], bb1.z), 0.f));
        s[7] = f2bf(fmaxf(fmaf(dv_self, acc[7], bb1.w), 0.f));
        *(u16x8*)&As[lrow * KP + l16 * 8] = s;  // 272-B row stride, 16-B aligned
    }

    // ---- last-wave tail: no block barrier ----
    __threadfence_block();  // drain this wave's LDS writes
    int lastv = 0;
    if (lane == 0) lastv = (atomicAdd(&done, 1) == 3) ? 1 : 0;
    lastv = __shfl(lastv, 0);
    if (!lastv) return;  // early waves free their SIMD slots

    const int lm = lane & 15;
    const int qd = lane >> 4;
#pragma unroll
    for (int wt = 0; wt < 4; ++wt) {  // all 4 column tiles -> LDS bounce
        const int col = wt * 16 + lm;
        f32x4 c4 = (f32x4){0.f, 0.f, 0.f, 0.f};
#pragma unroll
        for (int ks = 0; ks < 4; ++ks) {
            bf16x8 b = *(const bf16x8*)&W2t[(size_t)col * 128 + ks * 32 + qd * 8];
            bf16x8 a = *(const bf16x8*)&As[lm * KP + ks * 32 + qd * 8];
            c4 = __builtin_amdgcn_mfma_f32_16x16x32_bf16(a, b, c4, 0, 0, 0);
        }
#pragma unroll
        for (int r = 0; r < 4; ++r) {
            int r16 = qd * 4 + r;
            int row = m0 + r16;
            float dvr = (row < n) ? dinv[row] : 0.f;
            outb[r16 * 64 + col] = (short)f2bf(dvr * c4[r]);
        }
    }
    // coalesced full-row writes: 16 rows x 128 B = 2 iterations of 64 x uint4
#pragma unroll
    for (int it = 0; it < 2; ++it) {
        int idx = it * 64 + lane;
        int r16 = idx >> 3;
        int q = idx & 7;
        int row = m0 + r16;
        if (row < n)
            ((uint4*)(h2 + (size_t)row * 64))[q] = ((const uint4*)outb)[r16 * 8 + q];
    }
}

// 64-feature layer: 8 nodes/wave, 8 lanes/node (rows are 128 B). fp32 output.
// h2 is pre-scaled by dinv[row]. 16-deep register batches (R3 form) — R13's
// 4-wide low-VGPR revert measured slower: h2 is only partially L2-resident so
// per-wave in-flight depth dominates wave count here.
__global__ __launch_bounds__(256) void k_gather64(const int* __restrict__ rp,
                                                  const int* __restrict__ deg,
                                                  const int* __restrict__ eperm,
                                                  const float* __restrict__ dinv,
                                                  const uint4* __restrict__ h4,  // bf16 rows: 8 uint4/row
                                                  const float* __restrict__ bias,
                                                  float* __restrict__ out, int n) {
    const int t = threadIdx.x;
    const int lane = t & 63;
    const int l8 = lane & 7;
    const int gbase = lane & 56;
    const int node = blockIdx.x * 32 + (t >> 6) * 8 + (lane >> 3);
    const bool valid = node < n;

    int beg = 0, end = 0;
    if (valid) {
        beg = rp[node];
        end = beg + deg[node];
    }

    float acc[8];
#pragma unroll
    for (int i = 0; i < 8; ++i) acc[i] = 0.f;
    if (valid) accum_row(acc, h4[(size_t)node * 8 + l8]);  // self

    int j = beg;
    // ---- full 16-edge batches ----
    for (; j + 16 <= end; j += 16) {
        int ep0 = eperm[j + l8];
        int ep1 = eperm[j + 8 + l8];
        int idx[16];
#pragma unroll
        for (int k = 0; k < 8; ++k) idx[k] = __shfl(ep0, gbase + k);
#pragma unroll
        for (int k = 0; k < 8; ++k) idx[8 + k] = __shfl(ep1, gbase + k);
        uint4 v[16];
#pragma unroll
        for (int k = 0; k < 16; ++k) v[k] = h4[(size_t)idx[k] * 8 + l8];
#pragma unroll
        for (int k = 0; k < 16; ++k) accum_row(acc, v[k]);
    }
    int cnt = end - j;
    // ---- one 8-edge batch if present ----
    if (cnt >= 8) {
        int ep = eperm[j + l8];
        int idx[8];
#pragma unroll
        for (int k = 0; k < 8; ++k) idx[k] = __shfl(ep, gbase + k);
        uint4 v[8];
#pragma unroll
        for (int k = 0; k < 8; ++k) v[k] = h4[(size_t)idx[k] * 8 + l8];
#pragma unroll
        for (int k = 0; k < 8; ++k) accum_row(acc, v[k]);
        j += 8;
        cnt -= 8;
    }
    // ---- remainder (< 8 edges) ----
    if (cnt > 0) {
        int ep = eperm[j + (l8 < cnt ? l8 : cnt - 1)];
        int k = 0;
        for (; k + 4 <= cnt; k += 4) {
            int i0 = __shfl(ep, gbase + k);
            int i1 = __shfl(ep, gbase + k + 1);
            int i2 = __shfl(ep, gbase + k + 2);
            int i3 = __shfl(ep, gbase + k + 3);
            uint4 v0 = h4[(size_t)i0 * 8 + l8];
            uint4 v1 = h4[(size_t)i1 * 8 + l8];
            uint4 v2 = h4[(size_t)i2 * 8 + l8];
            uint4 v3 = h4[(size_t)i3 * 8 + l8];
            accum_row(acc, v0);
            accum_row(acc, v1);
            accum_row(acc, v2);
            accum_row(acc, v3);
        }
        for (; k < cnt; ++k) {
            int i0 = __shfl(ep, gbase + k);
            uint4 v0 = h4[(size_t)i0 * 8 + l8];
            accum_row(acc, v0);
        }
    }

    if (valid) {
        float dv = dinv[node];
        float4 b0 = ((const float4*)bias)[l8 * 2];
        float4 b1 = ((const float4*)bias)[l8 * 2 + 1];
        float4 o0, o1;
        o0.x = dv * acc[0] + b0.x; o0.y = dv * acc[1] + b0.y;
        o0.z = dv * acc[2] + b0.z; o0.w = dv * acc[3] + b0.w;
        o1.x = dv * acc[4] + b1.x; o1.y = dv * acc[5] + b1.y;
        o1.z = dv * acc[6] + b1.z; o1.w = dv * acc[7] + b1.w;
        float4* orow = (float4*)(out + (size_t)node * 64);
        orow[l8 * 2] = o0;
        orow[l8 * 2 + 1] = o1;
    }
}

// ---------------- launch ----------------

extern "C" void kernel_launch(void* const* d_in, const int* in_sizes, int n_in,
                              void* d_out, int out_size, void* d_ws, size_t ws_size,
                              hipStream_t stream) {
    const float* x  = (const float*)d_in[0];
    const int*   ei = (const int*)d_in[1];
    const float* W1 = (const float*)d_in[2];
    const float* b1 = (const float*)d_in[3];
    const float* W2 = (const float*)d_in[4];
    const float* b2 = (const float*)d_in[5];
    float* out = (float*)d_out;

    const int N = in_sizes[0] / 128;
    const int E = in_sizes[1] / 2;
    const int* src = ei;
    const int* dst = ei + E;
    const int NB = (N + 511) >> BSHIFT;                          // coarse buckets (<= 256)
    const int cap = (E + NB - 1) / NB + ((E / NB) >> 2) + 1024;  // padded window (mean+25%+1024)

    char* ws = (char*)d_ws;
    size_t off = 0;
    auto carve = [&](size_t bytes) -> void* {
        void* p = ws + off;
        off = (off + bytes + 255) & ~(size_t)255;
        return p;
    };
    float* dinv = (float*)carve((size_t)N * 4);
    int*   rp   = (int*)carve((size_t)N * 4);
    int*   deg  = (int*)carve((size_t)N * 4);
    int*   bcur = (int*)carve(256 * 4);
    unsigned int* binned = (unsigned int*)carve((size_t)NB * cap * 4);  // packed (dlocal,src)
    int*   eperm = (int*)carve((size_t)NB * cap * 4);                   // src, bucket-windowed
    unsigned short* h   = (unsigned short*)carve((size_t)N * 128 * 2);  // bf16 h = x@W1 (unscaled)
    unsigned short* h2  = (unsigned short*)carve((size_t)N * 64 * 2);   // bf16 layer-2 GEMM out
    unsigned short* W2t = (unsigned short*)carve(64 * 128 * 2);         // bf16 W2 transposed

    const int gMm = (N + 63) / 64;
    const int nbin = (E + BIN_CHUNK - 1) / BIN_CHUNK;

    // ---- CSR build overlapped with layer-1 GEMM ----
    hipMemsetAsync(bcur, 0, 256 * sizeof(int), stream);
    k_bin_gemm1<<<nbin + gMm, THREADS, 0, stream>>>(src, dst, bcur, binned, E, NB, cap,
                                                    x, W1, h, N, nbin);
    k_node_place<<<NB + 1, 512, 0, stream>>>(binned, bcur, cap, rp, deg, dinv, eperm, N,
                                             W2, W2t, NB);

    // ---- layer-1 gather fused with layer-2 GEMM (16-node blocks) ----
    k_gather_gemm2<<<(N + 15) / 16, THREADS, 0, stream>>>(rp, deg, eperm, dinv, (const uint4*)h,
                                                          b1, W2t, h2, N);

    // ---- layer-2 gather ----
    k_gather64<<<(N + 31) / 32, THREADS, 0, stream>>>(rp, deg, eperm, dinv, (const uint4*)h2, b2, out, N);
}